// Round 11
// baseline (265.060 us; speedup 1.0000x reference)
//
#include <hip/hip_runtime.h>
#include <hip/hip_fp16.h>

#define N_NODES 50000
#define N_EDGES 800000
#define DIM 128
#define LAYERS 4
#define SLOT 48           // padded slots per node; 4B/slot -> node region = 192B = 3 lines
#define EPB 8             // edges scanned per thread in bucket (N_EDGES % EPB == 0)
#define CNT_STRIDE 6250   // nodes per XCD class (50000/8); cnt permuted by d&7

#define BUCKET_BLOCKS 3128   // ceil(800000/(256*8)) * 8 = 391*8
#define WT_BLOCKS 256        // LAYERS*DIM*DIM/256
#define INIT_BLOCKS 3125     // N_NODES*DIM/8/256 (8 elems -> 8 fp8 bytes per thread)
#define LAYER_BLOCKS 1563    // ceil(50000/32): 32-node tiles

typedef __attribute__((ext_vector_type(8))) _Float16 half8;
typedef __attribute__((ext_vector_type(4))) float float4v;
typedef __attribute__((ext_vector_type(2))) float float2v;

// pack: src (u16) | w (fp16) << 16
__device__ __forceinline__ int pack_edge(int s, float w) {
    return (int)(((unsigned)__half_as_ushort(__float2half(w)) << 16) | (unsigned)(s & 0xFFFF));
}

// decode 8 fp8 (e4m3) packed in uint2 -> 8 floats
__device__ __forceinline__ void fp8x8_to_f32(uint2 v, float* f) {
    float2v a = __builtin_amdgcn_cvt_pk_f32_fp8(v.x, false);
    float2v b = __builtin_amdgcn_cvt_pk_f32_fp8(v.x, true);
    float2v c = __builtin_amdgcn_cvt_pk_f32_fp8(v.y, false);
    float2v d = __builtin_amdgcn_cvt_pk_f32_fp8(v.y, true);
    f[0] = a[0]; f[1] = a[1]; f[2] = b[0]; f[3] = b[1];
    f[4] = c[0]; f[5] = c[1]; f[6] = d[0]; f[7] = d[1];
}

// encode 8 floats -> 8 fp8 in uint2
__device__ __forceinline__ uint2 f32x8_to_fp8(const float* f) {
    unsigned lo = 0, hi = 0;
    lo = __builtin_amdgcn_cvt_pk_fp8_f32(f[0], f[1], lo, false);
    lo = __builtin_amdgcn_cvt_pk_fp8_f32(f[2], f[3], lo, true);
    hi = __builtin_amdgcn_cvt_pk_fp8_f32(f[4], f[5], hi, false);
    hi = __builtin_amdgcn_cvt_pk_fp8_f32(f[6], f[7], hi, true);
    return make_uint2(lo, hi);
}

// cnt PERMUTED: counter for node d at (d&7)*CNT_STRIDE + (d>>3) (r10: keeps
// each XCD's atomics on exclusive lines; small but free win).
__device__ __forceinline__ void bucket_one(int d, int s, float wv, int g,
                                           int* __restrict__ cnt,
                                           int* __restrict__ edge_buf) {
    if ((d & 7) == g) {
        int pos = atomicAdd(&cnt[g * CNT_STRIDE + (d >> 3)], 1);
        edge_buf[(size_t)d * SLOT + pos] = pack_edge(s, wv);
    }
}

// ---------------- fused prep: bucket + wt_prep + init, ONE dispatch --------
// bucket is pinned at ~44-46us (latency floor of 800K scattered atomic+store
// pairs -- r7/r10 falsified both the bytes and the cnt-ping-pong theories).
// wt + fp8 init hide inside its latency shadow. cnt zeroed by memset before.
__global__ __launch_bounds__(256) void prep_kernel(const int* __restrict__ src,
                                                   const int* __restrict__ dst,
                                                   const float* __restrict__ w,
                                                   int* __restrict__ cnt,
                                                   int* __restrict__ edge_buf,
                                                   const float* __restrict__ W,
                                                   __half* __restrict__ Wt,
                                                   const float4* __restrict__ x,
                                                   uint2* __restrict__ xh0) {
    int bid = blockIdx.x;
    int tid = threadIdx.x;
    if (bid < BUCKET_BLOCKS) {
        int g     = bid & 7;
        int chunk = bid >> 3;
        int base  = (chunk * 256 + tid) * EPB;
        if (base >= N_EDGES) return;
        int4   d4a = *(const int4*)(dst + base);
        int4   d4b = *(const int4*)(dst + base + 4);
        int4   s4a = *(const int4*)(src + base);
        int4   s4b = *(const int4*)(src + base + 4);
        float4 w4a = *(const float4*)(w + base);
        float4 w4b = *(const float4*)(w + base + 4);
        bucket_one(d4a.x, s4a.x, w4a.x, g, cnt, edge_buf);
        bucket_one(d4a.y, s4a.y, w4a.y, g, cnt, edge_buf);
        bucket_one(d4a.z, s4a.z, w4a.z, g, cnt, edge_buf);
        bucket_one(d4a.w, s4a.w, w4a.w, g, cnt, edge_buf);
        bucket_one(d4b.x, s4b.x, w4b.x, g, cnt, edge_buf);
        bucket_one(d4b.y, s4b.y, w4b.y, g, cnt, edge_buf);
        bucket_one(d4b.z, s4b.z, w4b.z, g, cnt, edge_buf);
        bucket_one(d4b.w, s4b.w, w4b.w, g, cnt, edge_buf);
    } else if (bid < BUCKET_BLOCKS + WT_BLOCKS) {
        int i = (bid - BUCKET_BLOCKS) * 256 + tid;   // < 65536 exact
        int l   = i >> 14;
        int rem = i & 16383;
        int k = rem >> 7;
        int n = rem & 127;
        Wt[(size_t)l * DIM * DIM + n * DIM + k] =
            __float2half(W[(size_t)l * DIM * DIM + k * DIM + n]);
    } else {
        int i = (bid - BUCKET_BLOCKS - WT_BLOCKS) * 256 + tid;  // < 800000 exact
        float4 a = x[(size_t)i * 2];
        float4 b = x[(size_t)i * 2 + 1];
        float f[8] = { a.x, a.y, a.z, a.w, b.x, b.y, b.z, b.w };
        xh0[i] = f32x8_to_fp8(f);
    }
}

// Process 8 edges for this lane's node with WIDE (uint4/16B) row chunks.
// 8-lane subgroup covers the 128B fp8 row; per-lane window = 8 x 16B = 128B
// in flight (2x the old uint2 form) at the SAME waves/SIMD (VGPR stays in
// the 65-128 bracket -- r7's batch16 crossed 128 and halved occupancy).
// Dead slots exec-masked off. m holds meta for slots base..base+7 at lane
// sgb|u (8-lane granule).
__device__ __forceinline__ void batch8w(const uint4* __restrict__ x16,
                                        int m, int base, int cnt_r, int sgb, int c2,
                                        float* accf, float& wsum) {
    uint4 v[8]; float wv[8];
    #pragma unroll
    for (int u = 0; u < 8; ++u) {
        int p = __shfl(m, sgb | u, 64);
        bool live = (base + u) < cnt_r;
        wv[u] = live
                  ? __half2float(__ushort_as_half((unsigned short)((unsigned)p >> 16)))
                  : 0.f;
        uint4 vv = make_uint4(0u, 0u, 0u, 0u);
        if (live) vv = x16[(size_t)(p & 0xFFFF) * 8 + c2];
        v[u] = vv;
    }
    #pragma unroll
    for (int u = 0; u < 8; ++u) {
        wsum += wv[u];
        float f[16];
        fp8x8_to_f32(make_uint2(v[u].x, v[u].y), f);
        fp8x8_to_f32(make_uint2(v[u].z, v[u].w), f + 8);
        #pragma unroll
        for (int t = 0; t < 16; ++t)
            accf[t] += wv[u] * f[t];
    }
}

// Fused layer: gather A = segsum(w * xin[src]) -> 32x128 fp16 tile in LDS ->
// MFMA A@W + win*b -> relu. 32-node tile: wave = 8 nodes x 8 lanes x 16B.
// FINAL=false: store layer output as fp8 to xout. FINAL=true: full GPR
// combine hidden = t0*X0 + t1*X1 + t2*X2 + t3*X3 + t4*out  (xin == X3).
// NOTE: plain __launch_bounds__(256) -- r4's cap spilled batch8. Never cap.
#define AP 136
template <bool FINAL>
__global__ __launch_bounds__(256) void layer_kernel(const uint4* __restrict__ xin16,
                                                    const int* __restrict__ cnt_arr,
                                                    const int* __restrict__ edge_buf,
                                                    const __half* __restrict__ Wt,
                                                    const float* __restrict__ bl,
                                                    uint2* __restrict__ xout,
                                                    float* __restrict__ hidden,
                                                    const float* __restrict__ temp,
                                                    const uint2* __restrict__ x0h,
                                                    const uint2* __restrict__ x1h,
                                                    const uint2* __restrict__ x2h) {
    __shared__ __half Ah[32][AP];
    __shared__ float winS[32];
    int tid  = threadIdx.x;
    int wave = tid >> 6;
    int lane = tid & 63;
    int sg  = lane >> 3;     // node subgroup 0..7
    int c2  = lane & 7;      // 16B chunk within fp8 row
    int sgb = lane & 0x38;
    int node_r = blockIdx.x * 32 + wave * 8 + sg;
    bool valid = node_r < N_NODES;
    int nidx = valid ? node_r : 0;

    // upfront, independent: slots 0-31 meta (4 regs at 8-lane granule) +
    // permuted cnt. slots 32-47 deferred into the rare branch.
    size_t mb = (size_t)nidx * SLOT;
    int m0 = edge_buf[mb + c2];
    int m1 = edge_buf[mb + 8 + c2];
    int m2 = edge_buf[mb + 16 + c2];
    int m3 = edge_buf[mb + 24 + c2];
    int cnt_r = valid ? cnt_arr[(nidx & 7) * CNT_STRIDE + (nidx >> 3)] : 0;

    int maxc = cnt_r;
    maxc = max(maxc, __shfl_xor(maxc, 8, 64));
    maxc = max(maxc, __shfl_xor(maxc, 16, 64));
    maxc = max(maxc, __shfl_xor(maxc, 32, 64));   // wave-uniform

    float accf[16];
    #pragma unroll
    for (int t = 0; t < 16; ++t) accf[t] = 0.f;
    float wsum = 0.f;

    batch8w(xin16, m0, 0, cnt_r, sgb, c2, accf, wsum);
    batch8w(xin16, m1, 8, cnt_r, sgb, c2, accf, wsum);
    if (maxc > 16) {
        batch8w(xin16, m2, 16, cnt_r, sgb, c2, accf, wsum);
        batch8w(xin16, m3, 24, cnt_r, sgb, c2, accf, wsum);
    }
    if (maxc > 32) {
        int m4 = edge_buf[mb + 32 + c2];
        int m5 = edge_buf[mb + 40 + c2];
        batch8w(xin16, m4, 32, cnt_r, sgb, c2, accf, wsum);
        batch8w(xin16, m5, 40, cnt_r, sgb, c2, accf, wsum);
    }

    // A tile (fp32 acc -> fp16) into LDS; 32 rows x 128 cols
    {
        union { __half2 hh[8]; float4 f4[2]; } ua;
        #pragma unroll
        for (int t = 0; t < 8; ++t)
            ua.hh[t] = __floats2half2_rn(accf[2 * t], accf[2 * t + 1]);
        int lr = wave * 8 + sg;
        *(float4*)&Ah[lr][c2 * 16]     = ua.f4[0];
        *(float4*)&Ah[lr][c2 * 16 + 8] = ua.f4[1];
        if (c2 == 0) winS[lr] = wsum;
    }
    __syncthreads();

    // MFMA tail: wave computes rows rt..rt+16 x cols ct..ct+64
    int am  = lane & 15;
    int ak8 = (lane >> 4) * 8;
    int rt  = (wave & 1) * 16;
    int ct  = (wave >> 1) * 64;
    float4v acc[4];
    #pragma unroll
    for (int j = 0; j < 4; ++j) acc[j] = (float4v)(0.f);
    #pragma unroll
    for (int kk = 0; kk < 4; ++kk) {
        int k0 = kk * 32 + ak8;
        half8 a = *(const half8*)&Ah[rt + am][k0];
        #pragma unroll
        for (int j = 0; j < 4; ++j) {
            half8 bj = *(const half8*)(Wt + (size_t)(ct + j * 16 + am) * DIM + k0);
            acc[j] = __builtin_amdgcn_mfma_f32_16x16x32_f16(a, bj, acc[j], 0, 0, 0);
        }
    }
    __syncthreads();

    // epilogue: + win*b, relu, back to LDS fp16
    {
        int q  = lane >> 4;
        int cc = lane & 15;
        #pragma unroll
        for (int j = 0; j < 4; ++j) {
            int col = ct + j * 16 + cc;
            float bv = bl[col];
            #pragma unroll
            for (int jj = 0; jj < 4; ++jj) {
                int row = rt + q * 4 + jj;
                Ah[row][col] = __float2half(fmaxf(acc[j][jj] + winS[row] * bv, 0.f));
            }
        }
    }
    __syncthreads();

    // 2 passes x (16 rows x 16 chunks): full-width coalesced access
    #pragma unroll
    for (int h = 0; h < 2; ++h) {
        int row = h * 16 + (tid >> 4);
        int ch  = tid & 15;
        int gnode = blockIdx.x * 32 + row;
        if (gnode >= N_NODES) continue;
        half8 hv = *(const half8*)&Ah[row][ch * 8];
        size_t ro = (size_t)gnode * 16 + ch;
        if constexpr (!FINAL) {
            float f[8];
            #pragma unroll
            for (int t = 0; t < 8; ++t) f[t] = (float)hv[t];
            xout[ro] = f32x8_to_fp8(f);
        } else {
            float t0 = temp[0], t1 = temp[1], t2 = temp[2], t3 = temp[3], t4 = temp[4];
            uint2 u0 = x0h[ro], u1 = x1h[ro], u2 = x2h[ro];
            uint2 u3 = ((const uint2*)xin16)[ro];
            float f0[8], f1[8], f2[8], f3[8];
            fp8x8_to_f32(u0, f0);
            fp8x8_to_f32(u1, f1);
            fp8x8_to_f32(u2, f2);
            fp8x8_to_f32(u3, f3);
            float out[8];
            #pragma unroll
            for (int t = 0; t < 8; ++t)
                out[t] = t0 * f0[t] + t1 * f1[t] + t2 * f2[t]
                       + t3 * f3[t] + t4 * (float)hv[t];
            size_t o = (size_t)gnode * DIM + ch * 8;
            *(float4*)(hidden + o)     = make_float4(out[0], out[1], out[2], out[3]);
            *(float4*)(hidden + o + 4) = make_float4(out[4], out[5], out[6], out[7]);
        }
    }
}

extern "C" void kernel_launch(void* const* d_in, const int* in_sizes, int n_in,
                              void* d_out, int out_size, void* d_ws, size_t ws_size,
                              hipStream_t stream) {
    const float* x    = (const float*)d_in[0];
    const float* w    = (const float*)d_in[1];
    const int*   src  = (const int*)d_in[2];
    const int*   dst  = (const int*)d_in[3];
    const float* W    = (const float*)d_in[4];
    const float* b    = (const float*)d_in[5];
    const float* temp = (const float*)d_in[6];
    float* hidden = (float*)d_out;

    char* ws = (char*)d_ws;
    // 4 fp8 x buffers: init->X0, L1 X0->X1, L2 X1->X2, L3 X2->X3,
    // L4 gathers X3 and combines X0..X3 + its own output into hidden.
    uint2* X0 = (uint2*)ws;                  ws += (size_t)N_NODES * DIM;   // fp8: 1B/elem
    uint2* X1 = (uint2*)ws;                  ws += (size_t)N_NODES * DIM;
    uint2* X2 = (uint2*)ws;                  ws += (size_t)N_NODES * DIM;
    uint2* X3 = (uint2*)ws;                  ws += (size_t)N_NODES * DIM;
    __half* Wt = (__half*)ws;                ws += (size_t)LAYERS * DIM * DIM * sizeof(__half);
    int* cnt = (int*)ws;                     ws += (size_t)N_NODES * sizeof(int);
    int* edge_buf = (int*)ws;                ws += (size_t)(N_NODES * SLOT + 64) * sizeof(int);

    hipMemsetAsync(cnt, 0, (size_t)N_NODES * sizeof(int), stream);
    prep_kernel<<<BUCKET_BLOCKS + WT_BLOCKS + INIT_BLOCKS, 256, 0, stream>>>(
        src, dst, w, cnt, edge_buf, W, Wt, (const float4*)x, X0);

    layer_kernel<false><<<LAYER_BLOCKS, 256, 0, stream>>>(
        (const uint4*)X0, cnt, edge_buf, Wt + 0 * DIM * DIM, b + 0 * DIM,
        X1, hidden, temp, nullptr, nullptr, nullptr);
    layer_kernel<false><<<LAYER_BLOCKS, 256, 0, stream>>>(
        (const uint4*)X1, cnt, edge_buf, Wt + 1 * DIM * DIM, b + 1 * DIM,
        X2, hidden, temp, nullptr, nullptr, nullptr);
    layer_kernel<false><<<LAYER_BLOCKS, 256, 0, stream>>>(
        (const uint4*)X2, cnt, edge_buf, Wt + 2 * DIM * DIM, b + 2 * DIM,
        X3, hidden, temp, nullptr, nullptr, nullptr);
    layer_kernel<true><<<LAYER_BLOCKS, 256, 0, stream>>>(
        (const uint4*)X3, cnt, edge_buf, Wt + 3 * DIM * DIM, b + 3 * DIM,
        nullptr, hidden, temp, X0, X1, X2);
}

// Round 12
// 254.156 us; speedup vs baseline: 1.0429x; 1.0429x over previous
//
#include <hip/hip_runtime.h>
#include <hip/hip_fp16.h>

#define N_NODES 50000
#define N_EDGES 800000
#define DIM 128
#define LAYERS 4
#define SLOT 48           // padded slots per node; 4B/slot -> node region = 192B = 3 lines
#define EPB 8             // edges scanned per thread in bucket (N_EDGES % EPB == 0)
#define CNT_STRIDE 6250   // nodes per XCD class (50000/8); cnt permuted by d&7

#define BUCKET_BLOCKS 3128   // ceil(800000/(256*8)) * 8 = 391*8
#define WT_BLOCKS 256        // LAYERS*DIM*DIM/256
#define INIT_BLOCKS 3125     // N_NODES*DIM/8/256 (8 elems -> 8 fp8 bytes per thread)

typedef __attribute__((ext_vector_type(8))) _Float16 half8;
typedef __attribute__((ext_vector_type(4))) float float4v;
typedef __attribute__((ext_vector_type(2))) float float2v;

// pack: src (u16) | w (fp16) << 16
__device__ __forceinline__ int pack_edge(int s, float w) {
    return (int)(((unsigned)__half_as_ushort(__float2half(w)) << 16) | (unsigned)(s & 0xFFFF));
}

// decode 8 fp8 (e4m3) packed in uint2 -> 8 floats
__device__ __forceinline__ void fp8x8_to_f32(uint2 v, float* f) {
    float2v a = __builtin_amdgcn_cvt_pk_f32_fp8(v.x, false);
    float2v b = __builtin_amdgcn_cvt_pk_f32_fp8(v.x, true);
    float2v c = __builtin_amdgcn_cvt_pk_f32_fp8(v.y, false);
    float2v d = __builtin_amdgcn_cvt_pk_f32_fp8(v.y, true);
    f[0] = a[0]; f[1] = a[1]; f[2] = b[0]; f[3] = b[1];
    f[4] = c[0]; f[5] = c[1]; f[6] = d[0]; f[7] = d[1];
}

// encode 8 floats -> 8 fp8 in uint2
__device__ __forceinline__ uint2 f32x8_to_fp8(const float* f) {
    unsigned lo = 0, hi = 0;
    lo = __builtin_amdgcn_cvt_pk_fp8_f32(f[0], f[1], lo, false);
    lo = __builtin_amdgcn_cvt_pk_fp8_f32(f[2], f[3], lo, true);
    hi = __builtin_amdgcn_cvt_pk_fp8_f32(f[4], f[5], hi, false);
    hi = __builtin_amdgcn_cvt_pk_fp8_f32(f[6], f[7], hi, true);
    return make_uint2(lo, hi);
}

// cnt PERMUTED: counter for node d at (d&7)*CNT_STRIDE + (d>>3) (r10: keeps
// each XCD's atomics on exclusive lines; small but free win).
__device__ __forceinline__ void bucket_one(int d, int s, float wv, int g,
                                           int* __restrict__ cnt,
                                           int* __restrict__ edge_buf) {
    if ((d & 7) == g) {
        int pos = atomicAdd(&cnt[g * CNT_STRIDE + (d >> 3)], 1);
        edge_buf[(size_t)d * SLOT + pos] = pack_edge(s, wv);
    }
}

// ---------------- fused prep: bucket + wt_prep + init, ONE dispatch --------
// bucket is pinned at ~44-46us (latency floor of 800K scattered atomic+store
// pairs -- r7/r10 falsified both the bytes and the cnt-ping-pong theories).
// wt + fp8 init hide inside its latency shadow. cnt zeroed by memset before.
__global__ __launch_bounds__(256) void prep_kernel(const int* __restrict__ src,
                                                   const int* __restrict__ dst,
                                                   const float* __restrict__ w,
                                                   int* __restrict__ cnt,
                                                   int* __restrict__ edge_buf,
                                                   const float* __restrict__ W,
                                                   __half* __restrict__ Wt,
                                                   const float4* __restrict__ x,
                                                   uint2* __restrict__ xh0) {
    int bid = blockIdx.x;
    int tid = threadIdx.x;
    if (bid < BUCKET_BLOCKS) {
        int g     = bid & 7;
        int chunk = bid >> 3;
        int base  = (chunk * 256 + tid) * EPB;
        if (base >= N_EDGES) return;
        int4   d4a = *(const int4*)(dst + base);
        int4   d4b = *(const int4*)(dst + base + 4);
        int4   s4a = *(const int4*)(src + base);
        int4   s4b = *(const int4*)(src + base + 4);
        float4 w4a = *(const float4*)(w + base);
        float4 w4b = *(const float4*)(w + base + 4);
        bucket_one(d4a.x, s4a.x, w4a.x, g, cnt, edge_buf);
        bucket_one(d4a.y, s4a.y, w4a.y, g, cnt, edge_buf);
        bucket_one(d4a.z, s4a.z, w4a.z, g, cnt, edge_buf);
        bucket_one(d4a.w, s4a.w, w4a.w, g, cnt, edge_buf);
        bucket_one(d4b.x, s4b.x, w4b.x, g, cnt, edge_buf);
        bucket_one(d4b.y, s4b.y, w4b.y, g, cnt, edge_buf);
        bucket_one(d4b.z, s4b.z, w4b.z, g, cnt, edge_buf);
        bucket_one(d4b.w, s4b.w, w4b.w, g, cnt, edge_buf);
    } else if (bid < BUCKET_BLOCKS + WT_BLOCKS) {
        int i = (bid - BUCKET_BLOCKS) * 256 + tid;   // < 65536 exact
        int l   = i >> 14;
        int rem = i & 16383;
        int k = rem >> 7;
        int n = rem & 127;
        Wt[(size_t)l * DIM * DIM + n * DIM + k] =
            __float2half(W[(size_t)l * DIM * DIM + k * DIM + n]);
    } else {
        int i = (bid - BUCKET_BLOCKS - WT_BLOCKS) * 256 + tid;  // < 800000 exact
        float4 a = x[(size_t)i * 2];
        float4 b = x[(size_t)i * 2 + 1];
        float f[8] = { a.x, a.y, a.z, a.w, b.x, b.y, b.z, b.w };
        xh0[i] = f32x8_to_fp8(f);
    }
}

// ---------------- gather pipeline: split load / fma phases -----------------
// r7/r11 lesson: in-flight bytes = waves/SIMD x window; widening the window
// crosses the 128-VGPR occupancy step and nets NEGATIVE. This round keeps the
// 8-slot window but runs TWO batches ping-pong so each batch's FMA phase
// executes under the other's load latency (duty cycle ~50% -> ~85%). Two
// named batches = static indexing (rule: runtime-indexed arrays -> scratch).
struct B8 { uint2 v[8]; float wv[8]; };

__device__ __forceinline__ void load8(B8& bt, const uint2* __restrict__ x8,
                                      int m, int base, int cnt_r, int r, int c) {
    #pragma unroll
    for (int u = 0; u < 8; ++u) {
        int jj = base + u;
        int p  = __shfl(m, (r << 4) | (jj & 15), 64);
        bool live = (jj < cnt_r);
        bt.wv[u] = live
                     ? __half2float(__ushort_as_half((unsigned short)((unsigned)p >> 16)))
                     : 0.f;
        uint2 vv = make_uint2(0u, 0u);
        if (live) vv = x8[(size_t)(p & 0xFFFF) * 16 + c];   // exec-masked: dead = no BW
        bt.v[u] = vv;
    }
}

__device__ __forceinline__ void fma8(const B8& bt, float* accf, float& wsum) {
    #pragma unroll
    for (int u = 0; u < 8; ++u) {
        wsum += bt.wv[u];
        float f[8];
        fp8x8_to_f32(bt.v[u], f);
        #pragma unroll
        for (int t = 0; t < 8; ++t)
            accf[t] += bt.wv[u] * f[t];
    }
}

// Fused layer: gather A = segsum(w * xin[src]) -> 16x128 fp16 tile in LDS ->
// MFMA A@W + win*b -> relu. (r9 split regressed; fused form kept.)
// FINAL=false: store layer output as fp8 to xout. FINAL=true: full GPR
// combine hidden = t0*X0 + t1*X1 + t2*X2 + t3*X3 + t4*out  (xin == X3).
// NOTE: plain __launch_bounds__(256). r4's (256,6) cap spilled. Never cap.
#define AP 136
template <bool FINAL>
__global__ __launch_bounds__(256) void layer_kernel(const uint2* __restrict__ xin8,
                                                    const int* __restrict__ cnt_arr,
                                                    const int* __restrict__ edge_buf,
                                                    const __half* __restrict__ Wt,
                                                    const float* __restrict__ bl,
                                                    uint2* __restrict__ xout,
                                                    float* __restrict__ hidden,
                                                    const float* __restrict__ temp,
                                                    const uint2* __restrict__ x0h,
                                                    const uint2* __restrict__ x1h,
                                                    const uint2* __restrict__ x2h) {
    __shared__ __half Ah[16][AP];
    __shared__ float winS[16];
    int tid  = threadIdx.x;
    int wave = tid >> 6;
    int lane = tid & 63;
    int r = lane >> 4;    // node subgroup 0..3
    int c = lane & 15;    // 8B chunk within fp8 row
    int node0  = blockIdx.x * 16 + wave * 4;
    int node_r = node0 + r;

    // upfront, independent: m0/m1 meta (slots 0-31) + permuted cnt (broadcast
    // per 16-lane group). m2 (slots 32-47) deferred into the rare branch.
    size_t mb = (size_t)node_r * SLOT;
    int m0 = edge_buf[mb + c];
    int m1 = edge_buf[mb + 16 + c];
    int cnt_r = cnt_arr[(node_r & 7) * CNT_STRIDE + (node_r >> 3)];

    int maxc = cnt_r;
    maxc = max(maxc, __shfl_xor(maxc, 16, 64));
    maxc = max(maxc, __shfl_xor(maxc, 32, 64));   // wave-uniform

    float accf[8];
    #pragma unroll
    for (int t = 0; t < 8; ++t) accf[t] = 0.f;
    float wsum = 0.f;

    // ping-pong pipeline: FMA of one batch overlaps the other's loads.
    B8 bA, bB;
    load8(bA, xin8, m0, 0, cnt_r, r, c);
    load8(bB, xin8, m0, 8, cnt_r, r, c);
    if (maxc <= 16) {
        fma8(bA, accf, wsum);
        fma8(bB, accf, wsum);
    } else {
        fma8(bA, accf, wsum);
        load8(bA, xin8, m1, 16, cnt_r, r, c);
        fma8(bB, accf, wsum);
        load8(bB, xin8, m1, 24, cnt_r, r, c);
        if (maxc > 32) {
            int m2 = edge_buf[mb + 32 + c];
            fma8(bA, accf, wsum);
            load8(bA, xin8, m2, 32, cnt_r, r, c);
            fma8(bB, accf, wsum);
            load8(bB, xin8, m2, 40, cnt_r, r, c);
        }
        fma8(bA, accf, wsum);
        fma8(bB, accf, wsum);
    }

    // A tile (fp32 acc -> fp16) into LDS; 16 rows x 128 cols
    union { __half2 hh[4]; float4 f4; } ua;
    ua.hh[0] = __floats2half2_rn(accf[0], accf[1]);
    ua.hh[1] = __floats2half2_rn(accf[2], accf[3]);
    ua.hh[2] = __floats2half2_rn(accf[4], accf[5]);
    ua.hh[3] = __floats2half2_rn(accf[6], accf[7]);
    int lr = wave * 4 + r;
    *(float4*)&Ah[lr][c * 8] = ua.f4;
    if (c == 0) winS[lr] = wsum;
    __syncthreads();

    // MFMA tail: wave computes rows 0..15 x cols [wave*32, wave*32+32)
    int am  = lane & 15;
    int ak8 = (lane >> 4) * 8;
    float4v acc0 = (float4v)(0.f), acc1 = (float4v)(0.f);
    #pragma unroll
    for (int kk = 0; kk < 4; ++kk) {
        int k0 = kk * 32 + ak8;
        half8 a  = *(const half8*)&Ah[am][k0];
        half8 b0 = *(const half8*)(Wt + (size_t)(wave * 32 + am) * DIM + k0);
        half8 b1 = *(const half8*)(Wt + (size_t)(wave * 32 + 16 + am) * DIM + k0);
        acc0 = __builtin_amdgcn_mfma_f32_16x16x32_f16(a, b0, acc0, 0, 0, 0);
        acc1 = __builtin_amdgcn_mfma_f32_16x16x32_f16(a, b1, acc1, 0, 0, 0);
    }
    __syncthreads();

    // epilogue: + win*b, relu, back to LDS fp16 for coalesced stores
    int q  = lane >> 4;
    int cc = lane & 15;
    {
        int col = wave * 32 + cc;
        float bv = bl[col];
        #pragma unroll
        for (int j = 0; j < 4; ++j) {
            int row = q * 4 + j;
            Ah[row][col] = __float2half(fmaxf(acc0[j] + winS[row] * bv, 0.f));
        }
        col = wave * 32 + 16 + cc;
        bv = bl[col];
        #pragma unroll
        for (int j = 0; j < 4; ++j) {
            int row = q * 4 + j;
            Ah[row][col] = __float2half(fmaxf(acc1[j] + winS[row] * bv, 0.f));
        }
    }
    __syncthreads();

    // 256 threads == 16 rows x 16 chunks
    int row = tid >> 4;
    int ch  = tid & 15;
    int gnode = blockIdx.x * 16 + row;
    half8 hv = *(const half8*)&Ah[row][ch * 8];
    size_t ro = (size_t)gnode * 16 + ch;

    if constexpr (!FINAL) {
        float f[8];
        #pragma unroll
        for (int t = 0; t < 8; ++t) f[t] = (float)hv[t];
        xout[ro] = f32x8_to_fp8(f);
    } else {
        float t0 = temp[0], t1 = temp[1], t2 = temp[2], t3 = temp[3], t4 = temp[4];
        uint2 u0 = x0h[ro], u1 = x1h[ro], u2 = x2h[ro], u3 = xin8[ro];
        float f0[8], f1[8], f2[8], f3[8];
        fp8x8_to_f32(u0, f0);
        fp8x8_to_f32(u1, f1);
        fp8x8_to_f32(u2, f2);
        fp8x8_to_f32(u3, f3);
        float out[8];
        #pragma unroll
        for (int t = 0; t < 8; ++t)
            out[t] = t0 * f0[t] + t1 * f1[t] + t2 * f2[t]
                   + t3 * f3[t] + t4 * (float)hv[t];
        size_t o = (size_t)gnode * DIM + ch * 8;
        *(float4*)(hidden + o)     = make_float4(out[0], out[1], out[2], out[3]);
        *(float4*)(hidden + o + 4) = make_float4(out[4], out[5], out[6], out[7]);
    }
}

extern "C" void kernel_launch(void* const* d_in, const int* in_sizes, int n_in,
                              void* d_out, int out_size, void* d_ws, size_t ws_size,
                              hipStream_t stream) {
    const float* x    = (const float*)d_in[0];
    const float* w    = (const float*)d_in[1];
    const int*   src  = (const int*)d_in[2];
    const int*   dst  = (const int*)d_in[3];
    const float* W    = (const float*)d_in[4];
    const float* b    = (const float*)d_in[5];
    const float* temp = (const float*)d_in[6];
    float* hidden = (float*)d_out;

    char* ws = (char*)d_ws;
    // 4 fp8 x buffers: init->X0, L1 X0->X1, L2 X1->X2, L3 X2->X3,
    // L4 gathers X3 and combines X0..X3 + its own output into hidden.
    uint2* X0 = (uint2*)ws;                  ws += (size_t)N_NODES * DIM;   // fp8: 1B/elem
    uint2* X1 = (uint2*)ws;                  ws += (size_t)N_NODES * DIM;
    uint2* X2 = (uint2*)ws;                  ws += (size_t)N_NODES * DIM;
    uint2* X3 = (uint2*)ws;                  ws += (size_t)N_NODES * DIM;
    __half* Wt = (__half*)ws;                ws += (size_t)LAYERS * DIM * DIM * sizeof(__half);
    int* cnt = (int*)ws;                     ws += (size_t)N_NODES * sizeof(int);
    int* edge_buf = (int*)ws;                ws += (size_t)(N_NODES * SLOT + 64) * sizeof(int);

    hipMemsetAsync(cnt, 0, (size_t)N_NODES * sizeof(int), stream);
    prep_kernel<<<BUCKET_BLOCKS + WT_BLOCKS + INIT_BLOCKS, 256, 0, stream>>>(
        src, dst, w, cnt, edge_buf, W, Wt, (const float4*)x, X0);

    const int layer_blocks = N_NODES / 16;   // 3125, exact
    layer_kernel<false><<<layer_blocks, 256, 0, stream>>>(
        X0, cnt, edge_buf, Wt + 0 * DIM * DIM, b + 0 * DIM,
        X1, hidden, temp, nullptr, nullptr, nullptr);
    layer_kernel<false><<<layer_blocks, 256, 0, stream>>>(
        X1, cnt, edge_buf, Wt + 1 * DIM * DIM, b + 1 * DIM,
        X2, hidden, temp, nullptr, nullptr, nullptr);
    layer_kernel<false><<<layer_blocks, 256, 0, stream>>>(
        X2, cnt, edge_buf, Wt + 2 * DIM * DIM, b + 2 * DIM,
        X3, hidden, temp, nullptr, nullptr, nullptr);
    layer_kernel<true><<<layer_blocks, 256, 0, stream>>>(
        X3, cnt, edge_buf, Wt + 3 * DIM * DIM, b + 3 * DIM,
        nullptr, hidden, temp, X0, X1, X2);
}

// Round 15
// 243.093 us; speedup vs baseline: 1.0904x; 1.0455x over previous
//
#include <hip/hip_runtime.h>
#include <hip/hip_fp16.h>

#define N_NODES 50000
#define N_EDGES 800000
#define DIM 128
#define LAYERS 4
#define SLOT 48           // padded slots per node; 4B/slot -> node region = 192B = 3 lines
#define EPB 8             // edges scanned per thread in bucket (N_EDGES % EPB == 0)
#define CNT_STRIDE 6250   // nodes per XCD class (50000/8); cnt permuted by d&7

#define BUCKET_BLOCKS 3128   // ceil(800000/(256*8)) * 8 = 391*8
#define WT_BLOCKS 256        // LAYERS*DIM*DIM/256
#define INIT_BLOCKS 3125     // N_NODES*DIM/8/256 (8 elems -> 8 fp8 bytes per thread)

typedef __attribute__((ext_vector_type(8))) _Float16 half8;
typedef __attribute__((ext_vector_type(4))) float float4v;
typedef __attribute__((ext_vector_type(2))) float float2v;

// pack: src (u16) | w (fp16) << 16
__device__ __forceinline__ int pack_edge(int s, float w) {
    return (int)(((unsigned)__half_as_ushort(__float2half(w)) << 16) | (unsigned)(s & 0xFFFF));
}

// decode 8 fp8 (e4m3) packed in uint2 -> 8 floats
__device__ __forceinline__ void fp8x8_to_f32(uint2 v, float* f) {
    float2v a = __builtin_amdgcn_cvt_pk_f32_fp8(v.x, false);
    float2v b = __builtin_amdgcn_cvt_pk_f32_fp8(v.x, true);
    float2v c = __builtin_amdgcn_cvt_pk_f32_fp8(v.y, false);
    float2v d = __builtin_amdgcn_cvt_pk_f32_fp8(v.y, true);
    f[0] = a[0]; f[1] = a[1]; f[2] = b[0]; f[3] = b[1];
    f[4] = c[0]; f[5] = c[1]; f[6] = d[0]; f[7] = d[1];
}

// encode 8 floats -> 8 fp8 in uint2
__device__ __forceinline__ uint2 f32x8_to_fp8(const float* f) {
    unsigned lo = 0, hi = 0;
    lo = __builtin_amdgcn_cvt_pk_fp8_f32(f[0], f[1], lo, false);
    lo = __builtin_amdgcn_cvt_pk_fp8_f32(f[2], f[3], lo, true);
    hi = __builtin_amdgcn_cvt_pk_fp8_f32(f[4], f[5], hi, false);
    hi = __builtin_amdgcn_cvt_pk_fp8_f32(f[6], f[7], hi, true);
    return make_uint2(lo, hi);
}

// cnt PERMUTED: counter for node d at (d&7)*CNT_STRIDE + (d>>3) (r10: keeps
// each XCD's atomics on exclusive lines; small but free win).
__device__ __forceinline__ void bucket_one(int d, int s, float wv, int g,
                                           int* __restrict__ cnt,
                                           int* __restrict__ edge_buf) {
    if ((d & 7) == g) {
        int pos = atomicAdd(&cnt[g * CNT_STRIDE + (d >> 3)], 1);
        edge_buf[(size_t)d * SLOT + pos] = pack_edge(s, wv);
    }
}

// ---------------- fused prep: bucket + wt_prep + init, ONE dispatch --------
// bucket is pinned at ~44-46us (latency floor of 800K scattered atomic+store
// pairs -- r7/r10 falsified both the bytes and the cnt-ping-pong theories).
// wt + fp8 init hide inside its latency shadow. cnt zeroed by memset before.
__global__ __launch_bounds__(256) void prep_kernel(const int* __restrict__ src,
                                                   const int* __restrict__ dst,
                                                   const float* __restrict__ w,
                                                   int* __restrict__ cnt,
                                                   int* __restrict__ edge_buf,
                                                   const float* __restrict__ W,
                                                   __half* __restrict__ Wt,
                                                   const float4* __restrict__ x,
                                                   uint2* __restrict__ xh0) {
    int bid = blockIdx.x;
    int tid = threadIdx.x;
    if (bid < BUCKET_BLOCKS) {
        int g     = bid & 7;
        int chunk = bid >> 3;
        int base  = (chunk * 256 + tid) * EPB;
        if (base >= N_EDGES) return;
        int4   d4a = *(const int4*)(dst + base);
        int4   d4b = *(const int4*)(dst + base + 4);
        int4   s4a = *(const int4*)(src + base);
        int4   s4b = *(const int4*)(src + base + 4);
        float4 w4a = *(const float4*)(w + base);
        float4 w4b = *(const float4*)(w + base + 4);
        bucket_one(d4a.x, s4a.x, w4a.x, g, cnt, edge_buf);
        bucket_one(d4a.y, s4a.y, w4a.y, g, cnt, edge_buf);
        bucket_one(d4a.z, s4a.z, w4a.z, g, cnt, edge_buf);
        bucket_one(d4a.w, s4a.w, w4a.w, g, cnt, edge_buf);
        bucket_one(d4b.x, s4b.x, w4b.x, g, cnt, edge_buf);
        bucket_one(d4b.y, s4b.y, w4b.y, g, cnt, edge_buf);
        bucket_one(d4b.z, s4b.z, w4b.z, g, cnt, edge_buf);
        bucket_one(d4b.w, s4b.w, w4b.w, g, cnt, edge_buf);
    } else if (bid < BUCKET_BLOCKS + WT_BLOCKS) {
        int i = (bid - BUCKET_BLOCKS) * 256 + tid;   // < 65536 exact
        int l   = i >> 14;
        int rem = i & 16383;
        int k = rem >> 7;
        int n = rem & 127;
        Wt[(size_t)l * DIM * DIM + n * DIM + k] =
            __float2half(W[(size_t)l * DIM * DIM + k * DIM + n]);
    } else {
        int i = (bid - BUCKET_BLOCKS - WT_BLOCKS) * 256 + tid;  // < 800000 exact
        float4 a = x[(size_t)i * 2];
        float4 b = x[(size_t)i * 2 + 1];
        float f[8] = { a.x, a.y, a.z, a.w, b.x, b.y, b.z, b.w };
        xh0[i] = f32x8_to_fp8(f);
    }
}

// Process 8 edges (slots base..base+7, meta register m) for this lane's node.
// r10-form batch8: sequential calls, NO manual pipelining -- the compiler
// already hoists the next batch's independent loads across this batch's FMAs
// (r12's explicit ping-pong added register state and regressed ~10us; r7/r11
// wider windows crossed the 128-VGPR occupancy step and regressed too).
// Dead slots: load exec-masked off (no bandwidth spent).
__device__ __forceinline__ void batch8(const uint2* __restrict__ x8,
                                       int m, int base, int cnt_r, int r, int c,
                                       float* accf, float& wsum) {
    uint2 v[8]; float wv[8];
    #pragma unroll
    for (int u = 0; u < 8; ++u) {
        int jj = base + u;
        int p  = __shfl(m, (r << 4) | (jj & 15), 64);
        bool live = (jj < cnt_r);
        wv[u] = live
                  ? __half2float(__ushort_as_half((unsigned short)((unsigned)p >> 16)))
                  : 0.f;
        uint2 vv = make_uint2(0u, 0u);
        if (live) vv = x8[(size_t)(p & 0xFFFF) * 16 + c];
        v[u] = vv;
    }
    #pragma unroll
    for (int u = 0; u < 8; ++u) {
        wsum += wv[u];
        float f[8];
        fp8x8_to_f32(v[u], f);
        #pragma unroll
        for (int t = 0; t < 8; ++t)
            accf[t] += wv[u] * f[t];
    }
}

// Fused layer: gather A = segsum(w * xin[src]) -> 16x128 fp16 tile in LDS ->
// MFMA A@W + win*b -> relu. (r9 split regressed; fused form kept.)
// FINAL=false: store layer output as fp8 to xout. FINAL=true: full GPR
// combine hidden = t0*X0 + t1*X1 + t2*X2 + t3*X3 + t4*out  (xin == X3);
// hidden stores are NONTEMPORAL via ext_vector float4v (r13: the builtin
// rejects HIP_vector_type float4) -- write-once output, never re-read.
// NOTE: plain __launch_bounds__(256). r4's (256,6) cap spilled. Never cap.
#define AP 136
template <bool FINAL>
__global__ __launch_bounds__(256) void layer_kernel(const uint2* __restrict__ xin8,
                                                    const int* __restrict__ cnt_arr,
                                                    const int* __restrict__ edge_buf,
                                                    const __half* __restrict__ Wt,
                                                    const float* __restrict__ bl,
                                                    uint2* __restrict__ xout,
                                                    float* __restrict__ hidden,
                                                    const float* __restrict__ temp,
                                                    const uint2* __restrict__ x0h,
                                                    const uint2* __restrict__ x1h,
                                                    const uint2* __restrict__ x2h) {
    __shared__ __half Ah[16][AP];
    __shared__ float winS[16];
    int tid  = threadIdx.x;
    int wave = tid >> 6;
    int lane = tid & 63;
    int r = lane >> 4;    // node subgroup 0..3
    int c = lane & 15;    // 8B chunk within fp8 row
    int node0  = blockIdx.x * 16 + wave * 4;
    int node_r = node0 + r;

    // upfront, independent: m0/m1 meta (slots 0-31) + permuted cnt (broadcast
    // per 16-lane group). m2 (slots 32-47) deferred into the rare branch.
    size_t mb = (size_t)node_r * SLOT;
    int m0 = edge_buf[mb + c];
    int m1 = edge_buf[mb + 16 + c];
    int cnt_r = cnt_arr[(node_r & 7) * CNT_STRIDE + (node_r >> 3)];

    int maxc = cnt_r;
    maxc = max(maxc, __shfl_xor(maxc, 16, 64));
    maxc = max(maxc, __shfl_xor(maxc, 32, 64));   // wave-uniform

    float accf[8];
    #pragma unroll
    for (int t = 0; t < 8; ++t) accf[t] = 0.f;
    float wsum = 0.f;

    batch8(xin8, m0, 0, cnt_r, r, c, accf, wsum);
    batch8(xin8, m0, 8, cnt_r, r, c, accf, wsum);
    if (maxc > 16) {
        batch8(xin8, m1, 16, cnt_r, r, c, accf, wsum);
        batch8(xin8, m1, 24, cnt_r, r, c, accf, wsum);
    }
    if (maxc > 32) {
        int m2 = edge_buf[mb + 32 + c];
        batch8(xin8, m2, 32, cnt_r, r, c, accf, wsum);
        batch8(xin8, m2, 40, cnt_r, r, c, accf, wsum);
    }

    // A tile (fp32 acc -> fp16) into LDS; 16 rows x 128 cols
    union { __half2 hh[4]; float4 f4; } ua;
    ua.hh[0] = __floats2half2_rn(accf[0], accf[1]);
    ua.hh[1] = __floats2half2_rn(accf[2], accf[3]);
    ua.hh[2] = __floats2half2_rn(accf[4], accf[5]);
    ua.hh[3] = __floats2half2_rn(accf[6], accf[7]);
    int lr = wave * 4 + r;
    *(float4*)&Ah[lr][c * 8] = ua.f4;
    if (c == 0) winS[lr] = wsum;
    __syncthreads();

    // MFMA tail: wave computes rows 0..15 x cols [wave*32, wave*32+32)
    int am  = lane & 15;
    int ak8 = (lane >> 4) * 8;
    float4v acc0 = (float4v)(0.f), acc1 = (float4v)(0.f);
    #pragma unroll
    for (int kk = 0; kk < 4; ++kk) {
        int k0 = kk * 32 + ak8;
        half8 a  = *(const half8*)&Ah[am][k0];
        half8 b0 = *(const half8*)(Wt + (size_t)(wave * 32 + am) * DIM + k0);
        half8 b1 = *(const half8*)(Wt + (size_t)(wave * 32 + 16 + am) * DIM + k0);
        acc0 = __builtin_amdgcn_mfma_f32_16x16x32_f16(a, b0, acc0, 0, 0, 0);
        acc1 = __builtin_amdgcn_mfma_f32_16x16x32_f16(a, b1, acc1, 0, 0, 0);
    }
    __syncthreads();

    // epilogue: + win*b, relu, back to LDS fp16 for coalesced stores
    int q  = lane >> 4;
    int cc = lane & 15;
    {
        int col = wave * 32 + cc;
        float bv = bl[col];
        #pragma unroll
        for (int j = 0; j < 4; ++j) {
            int row = q * 4 + j;
            Ah[row][col] = __float2half(fmaxf(acc0[j] + winS[row] * bv, 0.f));
        }
        col = wave * 32 + 16 + cc;
        bv = bl[col];
        #pragma unroll
        for (int j = 0; j < 4; ++j) {
            int row = q * 4 + j;
            Ah[row][col] = __float2half(fmaxf(acc1[j] + winS[row] * bv, 0.f));
        }
    }
    __syncthreads();

    // 256 threads == 16 rows x 16 chunks
    int row = tid >> 4;
    int ch  = tid & 15;
    int gnode = blockIdx.x * 16 + row;
    half8 hv = *(const half8*)&Ah[row][ch * 8];
    size_t ro = (size_t)gnode * 16 + ch;

    if constexpr (!FINAL) {
        float f[8];
        #pragma unroll
        for (int t = 0; t < 8; ++t) f[t] = (float)hv[t];
        xout[ro] = f32x8_to_fp8(f);
    } else {
        float t0 = temp[0], t1 = temp[1], t2 = temp[2], t3 = temp[3], t4 = temp[4];
        uint2 u0 = x0h[ro], u1 = x1h[ro], u2 = x2h[ro], u3 = xin8[ro];
        float f0[8], f1[8], f2[8], f3[8];
        fp8x8_to_f32(u0, f0);
        fp8x8_to_f32(u1, f1);
        fp8x8_to_f32(u2, f2);
        fp8x8_to_f32(u3, f3);
        float out[8];
        #pragma unroll
        for (int t = 0; t < 8; ++t)
            out[t] = t0 * f0[t] + t1 * f1[t] + t2 * f2[t]
                   + t3 * f3[t] + t4 * (float)hv[t];
        size_t o = (size_t)gnode * DIM + ch * 8;
        float4v h0 = { out[0], out[1], out[2], out[3] };
        float4v h1 = { out[4], out[5], out[6], out[7] };
        __builtin_nontemporal_store(h0, (float4v*)(hidden + o));
        __builtin_nontemporal_store(h1, (float4v*)(hidden + o + 4));
    }
}

extern "C" void kernel_launch(void* const* d_in, const int* in_sizes, int n_in,
                              void* d_out, int out_size, void* d_ws, size_t ws_size,
                              hipStream_t stream) {
    const float* x    = (const float*)d_in[0];
    const float* w    = (const float*)d_in[1];
    const int*   src  = (const int*)d_in[2];
    const int*   dst  = (const int*)d_in[3];
    const float* W    = (const float*)d_in[4];
    const float* b    = (const float*)d_in[5];
    const float* temp = (const float*)d_in[6];
    float* hidden = (float*)d_out;

    char* ws = (char*)d_ws;
    // 4 fp8 x buffers: init->X0, L1 X0->X1, L2 X1->X2, L3 X2->X3,
    // L4 gathers X3 and combines X0..X3 + its own output into hidden.
    uint2* X0 = (uint2*)ws;                  ws += (size_t)N_NODES * DIM;   // fp8: 1B/elem
    uint2* X1 = (uint2*)ws;                  ws += (size_t)N_NODES * DIM;
    uint2* X2 = (uint2*)ws;                  ws += (size_t)N_NODES * DIM;
    uint2* X3 = (uint2*)ws;                  ws += (size_t)N_NODES * DIM;
    __half* Wt = (__half*)ws;                ws += (size_t)LAYERS * DIM * DIM * sizeof(__half);
    int* cnt = (int*)ws;                     ws += (size_t)N_NODES * sizeof(int);
    int* edge_buf = (int*)ws;                ws += (size_t)(N_NODES * SLOT + 64) * sizeof(int);

    hipMemsetAsync(cnt, 0, (size_t)N_NODES * sizeof(int), stream);
    prep_kernel<<<BUCKET_BLOCKS + WT_BLOCKS + INIT_BLOCKS, 256, 0, stream>>>(
        src, dst, w, cnt, edge_buf, W, Wt, (const float4*)x, X0);

    const int layer_blocks = N_NODES / 16;   // 3125, exact
    layer_kernel<false><<<layer_blocks, 256, 0, stream>>>(
        X0, cnt, edge_buf, Wt + 0 * DIM * DIM, b + 0 * DIM,
        X1, hidden, temp, nullptr, nullptr, nullptr);
    layer_kernel<false><<<layer_blocks, 256, 0, stream>>>(
        X1, cnt, edge_buf, Wt + 1 * DIM * DIM, b + 1 * DIM,
        X2, hidden, temp, nullptr, nullptr, nullptr);
    layer_kernel<false><<<layer_blocks, 256, 0, stream>>>(
        X2, cnt, edge_buf, Wt + 2 * DIM * DIM, b + 2 * DIM,
        X3, hidden, temp, nullptr, nullptr, nullptr);
    layer_kernel<true><<<layer_blocks, 256, 0, stream>>>(
        X3, cnt, edge_buf, Wt + 3 * DIM * DIM, b + 3 * DIM,
        nullptr, hidden, temp, X0, X1, X2);
}